// Round 4
// baseline (325.043 us; speedup 1.0000x reference)
//
#include <hip/hip_runtime.h>
#include <hip/hip_bf16.h>

typedef __attribute__((ext_vector_type(8))) short bf16x8;
typedef __attribute__((ext_vector_type(4))) float f32x4;
typedef __attribute__((ext_vector_type(4))) short s16x4;

__device__ __forceinline__ short f2bf(float f) {
  union { float f; unsigned u; } v; v.f = f;
  unsigned r = v.u + 0x7fffu + ((v.u >> 16) & 1u);
  return (short)(r >> 16);
}

__device__ __forceinline__ float bf2f(short s) {
  union { float f; unsigned u; } v; v.u = ((unsigned)(unsigned short)s) << 16;
  return v.f;
}

#define GLD_LDS(g, l) __builtin_amdgcn_global_load_lds( \
    (const __attribute__((address_space(1))) void*)(g), \
    (__attribute__((address_space(3))) void*)(l), 16, 0, 0)

// ---------------- fp32 -> bf16 convert (x) ----------------
__global__ void convx_k(const float* __restrict__ x, short* __restrict__ xb, int n4) {
  int i = blockIdx.x * blockDim.x + threadIdx.x;
  const int stride = gridDim.x * blockDim.x;
  for (; i < n4; i += stride) {
    float4 v = ((const float4*)x)[i];
    s16x4 o;
    o[0] = f2bf(v.x); o[1] = f2bf(v.y); o[2] = f2bf(v.z); o[3] = f2bf(v.w);
    ((s16x4*)xb)[i] = o;
  }
}

// ------- transpose + convert weights: Wt[d][c] = W[c][d] (+I for z<5; g-fold z==5) -------
__global__ void twc_k(const float* __restrict__ Wq, const float* __restrict__ Wk,
                      const float* __restrict__ Wv, const float* __restrict__ Wo,
                      const float* __restrict__ lng, short* __restrict__ dst) {
  __shared__ float tile[32][33];
  const int z = blockIdx.z;
  const float* src = (z == 0) ? Wq
                   : (z == 1) ? Wk
                   : (z == 2) ? (Wk + 1048576)
                   : (z == 3) ? Wv
                   : (z == 4) ? (Wv + 1048576)
                   : Wo;
  short* d = dst + (size_t)z * 1048576;
  const int tx = threadIdx.x, ty = threadIdx.y;
  const int c0 = blockIdx.y * 32, d0 = blockIdx.x * 32;
#pragma unroll
  for (int i = 0; i < 4; ++i)
    tile[ty + i * 8][tx] = src[(size_t)(c0 + ty + i * 8) * 1024 + d0 + tx];
  __syncthreads();
#pragma unroll
  for (int i = 0; i < 4; ++i) {
    const int cc = c0 + tx;
    const int dd = d0 + ty + i * 8;
    float v = tile[tx][ty + i * 8];
    if (z < 5) {
      if (cc == dd) v += 1.0f;  // fold residual: x + x@W = x@(I+W)
    } else {
      v *= lng[cc];             // fold LN gain into Wo
    }
    d[(size_t)dd * 1024 + cc] = f2bf(v);
  }
}

// ------- u[d] = sum_c g[c]Wo[c,d];  t[d] = sum_c b[c]Wo[c,d] + bo[d] -------
__global__ __launch_bounds__(256)
void ut_k(const float* __restrict__ Wo, const float* __restrict__ lng,
          const float* __restrict__ lnb, const float* __restrict__ bo,
          float* __restrict__ u, float* __restrict__ t) {
  const int dl = threadIdx.x & 63;
  const int dd = blockIdx.x * 64 + dl;
  const int part = threadIdx.x >> 6;
  float su = 0.f, st = 0.f;
  for (int c = part * 256; c < part * 256 + 256; ++c) {
    const float w = Wo[(size_t)c * 1024 + dd];
    su += lng[c] * w;
    st += lnb[c] * w;
  }
  __shared__ float rs[4][64], rt[4][64];
  rs[part][dl] = su; rt[part][dl] = st;
  __syncthreads();
  if (part == 0) {
    su = rs[0][dl] + rs[1][dl] + rs[2][dl] + rs[3][dl];
    st = rt[0][dl] + rt[1][dl] + rt[2][dl] + rt[3][dl];
    u[dd] = su;
    t[dd] = st + bo[dd];
  }
}

// ---------------- 256x256-tile BK=32 4-buffer counted-vmcnt pipelined GEMM ----------------
// LDS: 4 buffers x (A 16KB + B 16KB). Pair-line swizzled layout:
//   element (row R, k-chunk khi[0..3] of 8 shorts) at shorts  R*32 + ((khi ^ ((R>>1)&3))<<3)
// global_load_lds dest stays linear; the inverse permutation is applied to the
// global source k-offset (both-sides rule).
// MODE 0: fused 5-proj (w==0 -> q bf16 row-major; w>=1 -> kv transposed scaled, LDS bounce)
// MODE 1: final GEMM with folded LayerNorm epilogue, fp32 out.
template <int MODE>
__global__ __launch_bounds__(512, 2)
void gemm256p_k(const short* __restrict__ A, const short* __restrict__ WT,
                const float* __restrict__ bq, const float* __restrict__ bk,
                const float* __restrict__ bv,
                short* __restrict__ q, short* __restrict__ kvt,
                const float* __restrict__ mu, const float* __restrict__ rstd,
                const float* __restrict__ uu, const float* __restrict__ tt,
                float* __restrict__ fout) {
  extern __shared__ short lds[];  // 131072 B = 4 x (8192 A-shorts + 8192 B-shorts)
  const int tid = threadIdx.x;
  const int lane = tid & 63;
  const int wv = tid >> 6;   // 0..7
  const int wm = wv >> 2;    // 0..1
  const int wn = wv & 3;     // 0..3

  int bm, w, bn;
  if (MODE == 0) {
    const int swz = (blockIdx.x & 7) * 160 + (blockIdx.x >> 3);  // XCD-bijective (1280%8==0)
    const int bng = swz >> 6;  // 0..19
    bm = swz & 63;
    w = bng >> 2; bn = bng & 3;
  } else {
    const int swz = (blockIdx.x & 7) * 32 + (blockIdx.x >> 3);   // 256 blocks
    bm = swz & 63; bn = swz >> 6; w = 0;
  }
  const int bm0 = bm << 8;
  const int bn0 = bn << 8;
  const short* Bt = WT + ((size_t)w << 20);

  // staging lane decomposition (pair-line layout, dest linear = lane*16B)
  const int lrow = ((lane >> 3) << 1) | ((lane >> 2) & 1);
  const int kc = ((lane & 3) ^ ((lane >> 3) & 3)) << 3;

  f32x4 acc[8][4];
#pragma unroll
  for (int i = 0; i < 8; ++i)
#pragma unroll
    for (int j = 0; j < 4; ++j) acc[i][j] = f32x4{0.f, 0.f, 0.f, 0.f};

  auto stage = [&](int buf, int t) {
    const int k0 = t << 5;
    short* ab = lds + (buf << 14);
    short* bb = ab + 8192;
#pragma unroll
    for (int c = 0; c < 2; ++c) {
      const int u = wv * 2 + c;               // 16 units of 16 rows
      const int R = (u << 4) + lrow;
      GLD_LDS(A + (size_t)(bm0 + R) * 1024 + k0 + kc, ab + (u << 9));
      GLD_LDS(Bt + (size_t)(bn0 + R) * 1024 + k0 + kc, bb + (u << 9));
    }
  };

  const int cl = lane & 15;
  const int khi = lane >> 4;  // 0..3

  auto compute = [&](int buf) {
    const short* ab = lds + (buf << 14);
    const short* bb = ab + 8192;
    bf16x8 af[8], bfr[4];
#pragma unroll
    for (int i = 0; i < 8; ++i) {
      const int R = (wm << 7) + (i << 4) + cl;
      af[i] = *(const bf16x8*)(ab + (R << 5) + ((khi ^ ((R >> 1) & 3)) << 3));
    }
#pragma unroll
    for (int j = 0; j < 4; ++j) {
      const int C = (wn << 6) + (j << 4) + cl;
      bfr[j] = *(const bf16x8*)(bb + (C << 5) + ((khi ^ ((C >> 1) & 3)) << 3));
    }
#pragma unroll
    for (int i = 0; i < 8; ++i)
#pragma unroll
      for (int j = 0; j < 4; ++j)
        acc[i][j] = __builtin_amdgcn_mfma_f32_16x16x32_bf16(af[i], bfr[j], acc[i][j], 0, 0, 0);
  };

  // prologue: tiles 0,1 staged; wait tile0 (4 remain in flight)
  stage(0, 0);
  stage(1, 1);
  asm volatile("s_waitcnt vmcnt(4)" ::: "memory");
  __builtin_amdgcn_s_barrier();
  // steady state: stage t+2, compute t, retire t+1's 4 loads (t+2's stay in flight)
#pragma unroll 1
  for (int t = 0; t < 30; ++t) {
    stage((t + 2) & 3, t + 2);
    compute(t & 3);
    asm volatile("s_waitcnt vmcnt(4)" ::: "memory");
    __builtin_amdgcn_s_barrier();
  }
  compute(2);  // tile 30
  asm volatile("s_waitcnt vmcnt(0)" ::: "memory");
  __builtin_amdgcn_s_barrier();
  compute(3);  // tile 31
  __builtin_amdgcn_s_barrier();

  if (MODE == 1) {
#pragma unroll
    for (int i = 0; i < 8; ++i) {
      const int rowb = bm0 + (wm << 7) + (i << 4) + (khi << 2);
      const float4 m4 = *(const float4*)(mu + rowb);
      const float4 s4 = *(const float4*)(rstd + rowb);
#pragma unroll
      for (int j = 0; j < 4; ++j) {
        const int col = bn0 + (wn << 6) + (j << 4) + cl;
        const float uc = uu[col];
        const float tc = tt[col];
        fout[(size_t)(rowb + 0) * 1024 + col] = s4.x * (acc[i][j][0] - m4.x * uc) + tc;
        fout[(size_t)(rowb + 1) * 1024 + col] = s4.y * (acc[i][j][1] - m4.y * uc) + tc;
        fout[(size_t)(rowb + 2) * 1024 + col] = s4.z * (acc[i][j][2] - m4.z * uc) + tc;
        fout[(size_t)(rowb + 3) * 1024 + col] = s4.w * (acc[i][j][3] - m4.w * uc) + tc;
      }
    }
    return;
  }

  if (w == 0) {
#pragma unroll
    for (int i = 0; i < 8; ++i)
#pragma unroll
      for (int j = 0; j < 4; ++j) {
        const int col = bn0 + (wn << 6) + (j << 4) + cl;
        const int rowb = bm0 + (wm << 7) + (i << 4) + (khi << 2);
        const float bi = bq[col];
#pragma unroll
        for (int r = 0; r < 4; ++r)
          q[(size_t)(rowb + r) * 1024 + col] = f2bf(acc[i][j][r] + bi);
      }
    return;
  }

  // kv: transposed coalesced store via LDS bounce
  const float scale = 0.015625f;  // 1/sqrt(4096)
  const float* bias = (w <= 2) ? bk + ((w - 1) << 10) : bv + ((w - 3) << 10);
  short* kdst = kvt + (((size_t)(w - 1)) << 24);
  const int b = bm0 >> 12;
  const int nb = bm0 & 4095;
#pragma unroll 1
  for (int ch = 0; ch < 2; ++ch) {
    if ((wn >> 1) == ch) {
#pragma unroll
      for (int i = 0; i < 8; ++i)
#pragma unroll
        for (int j = 0; j < 4; ++j) {
          const int lcol = ((wn & 1) << 6) + (j << 4) + cl;       // 0..127
          const int lrow2 = (wm << 7) + (i << 4) + (khi << 2);    // 0..252
          const float bi = bias[bn0 + (ch << 7) + lcol];
          s16x4 pk;
#pragma unroll
          for (int r = 0; r < 4; ++r) pk[r] = f2bf((acc[i][j][r] + bi) * scale);
          *(s16x4*)(lds + lcol * 260 + lrow2) = pk;
        }
    }
    __syncthreads();
#pragma unroll
    for (int it = 0; it < 16; ++it) {
      const int lcol = (it << 3) + wv;
      const int n0 = lane << 2;
      const s16x4 pk = *(const s16x4*)(lds + lcol * 260 + n0);
      const int colg = bn0 + (ch << 7) + lcol;
      const int h = colg >> 6, dd = colg & 63;
      *(s16x4*)(kdst + (((size_t)((b * 16 + h) * 64 + dd)) << 12) + nb + n0) = pk;
    }
    __syncthreads();
  }
}

// ---------------- states partials: P[c][k][bh][d][e] += ks^T * vs over n-chunk ----------------
__global__ __launch_bounds__(256)
void states_k(const short* __restrict__ kst, const short* __restrict__ vst,
              float* __restrict__ P) {
  __shared__ short Al[64 * 40];
  __shared__ short Bl[64 * 40];
  const int tid = threadIdx.x;
  const int lane = tid & 63;
  const int wid = tid >> 6;
  const int bh = blockIdx.x;
  const int ch = blockIdx.y;
  const int kk = blockIdx.z;
  const size_t base = ((size_t)(kk * 64 + bh)) << 18;
  const int n0 = ch << 10;
  const int srow = tid >> 2;
  const int sch = (tid & 3) << 3;
  const size_t soff = base + (size_t)srow * 4096 + n0 + sch;

  f32x4 acc[4];
#pragma unroll
  for (int j = 0; j < 4; ++j) acc[j] = f32x4{0.f, 0.f, 0.f, 0.f};

#pragma unroll 1
  for (int ns = 0; ns < 1024; ns += 32) {
    bf16x8 va = *(const bf16x8*)(kst + soff + ns);
    bf16x8 vb = *(const bf16x8*)(vst + soff + ns);
    __syncthreads();
    *(bf16x8*)(Al + srow * 40 + sch) = va;
    *(bf16x8*)(Bl + srow * 40 + sch) = vb;
    __syncthreads();
    bf16x8 a = *(const bf16x8*)(Al + (wid * 16 + (lane & 15)) * 40 + ((lane >> 4) << 3));
#pragma unroll
    for (int j = 0; j < 4; ++j) {
      bf16x8 b = *(const bf16x8*)(Bl + (j * 16 + (lane & 15)) * 40 + ((lane >> 4) << 3));
      acc[j] = __builtin_amdgcn_mfma_f32_16x16x32_bf16(a, b, acc[j], 0, 0, 0);
    }
  }
  const size_t pb = ((size_t)((ch * 2 + kk) * 64 + bh)) << 12;
  const int r0 = wid * 16 + ((lane >> 4) << 2);
  const int cl = lane & 15;
#pragma unroll
  for (int j = 0; j < 4; ++j)
#pragma unroll
    for (int r = 0; r < 4; ++r)
      P[pb + (size_t)(r0 + r) * 64 + j * 16 + cl] = acc[j][r];
}

// ---------------- reduce chunks, state = S0*S1, write transposed bf16 ----------------
__global__ __launch_bounds__(256)
void state_mul_k(const float* __restrict__ P, short* __restrict__ stt) {
  const int bh = blockIdx.x;
  for (int t = threadIdx.x; t < 4096; t += 256) {
    float s0 = 0.f, s1 = 0.f;
#pragma unroll
    for (int c = 0; c < 4; ++c) {
      s0 += P[(((size_t)((c * 2 + 0) * 64 + bh)) << 12) + t];
      s1 += P[(((size_t)((c * 2 + 1) * 64 + bh)) << 12) + t];
    }
    const int d = t >> 6, e = t & 63;
    stt[(bh << 12) + (e << 6) + d] = f2bf(s0 * s1);
  }
}

// ---------------- out_att = q @ state per (b,h) -> bf16 ----------------
__global__ __launch_bounds__(256)
void attn_k(const short* __restrict__ q, const short* __restrict__ stt,
            short* __restrict__ oat) {
  __shared__ short Al[128 * 72];
  __shared__ short Bl[64 * 72];
  const int tid = threadIdx.x;
  const int lane = tid & 63;
  const int wid = tid >> 6;
  const int mc = blockIdx.x;
  const int bh = blockIdx.y;
  const int b = bh >> 4, h = bh & 15;
  const size_t qbase = ((size_t)(b * 4096 + mc * 128)) * 1024 + h * 64;
#pragma unroll
  for (int s = 0; s < 4; ++s) {
    const int idx = tid + s * 256;
    const int row = idx >> 3, cc = (idx & 7) << 3;
    *(bf16x8*)(Al + row * 72 + cc) = *(const bf16x8*)(q + qbase + (size_t)row * 1024 + cc);
  }
#pragma unroll
  for (int s = 0; s < 2; ++s) {
    const int idx = tid + s * 256;
    const int row = idx >> 3, cc = (idx & 7) << 3;
    *(bf16x8*)(Bl + row * 72 + cc) = *(const bf16x8*)(stt + (bh << 12) + (row << 6) + cc);
  }
  __syncthreads();
  f32x4 acc[2][4];
#pragma unroll
  for (int i = 0; i < 2; ++i)
#pragma unroll
    for (int j = 0; j < 4; ++j) acc[i][j] = f32x4{0.f, 0.f, 0.f, 0.f};
#pragma unroll
  for (int ks = 0; ks < 2; ++ks) {
    bf16x8 a0 = *(const bf16x8*)(Al + (wid * 32 + (lane & 15)) * 72 + ks * 32 + ((lane >> 4) << 3));
    bf16x8 a1 = *(const bf16x8*)(Al + (wid * 32 + 16 + (lane & 15)) * 72 + ks * 32 + ((lane >> 4) << 3));
#pragma unroll
    for (int j = 0; j < 4; ++j) {
      bf16x8 bb = *(const bf16x8*)(Bl + (j * 16 + (lane & 15)) * 72 + ks * 32 + ((lane >> 4) << 3));
      acc[0][j] = __builtin_amdgcn_mfma_f32_16x16x32_bf16(a0, bb, acc[0][j], 0, 0, 0);
      acc[1][j] = __builtin_amdgcn_mfma_f32_16x16x32_bf16(a1, bb, acc[1][j], 0, 0, 0);
    }
  }
  const int r0 = wid * 32 + ((lane >> 4) << 2);
  const int cl = lane & 15;
#pragma unroll
  for (int i = 0; i < 2; ++i)
#pragma unroll
    for (int j = 0; j < 4; ++j)
#pragma unroll
      for (int r = 0; r < 4; ++r) {
        const int row = b * 4096 + mc * 128 + r0 + i * 16 + r;
        oat[(size_t)row * 1024 + h * 64 + j * 16 + cl] = f2bf(acc[i][j][r]);
      }
}

// ---------------- per-row mean / rstd of bf16 oat ----------------
__global__ __launch_bounds__(256)
void stats_k(const short* __restrict__ oat, float* __restrict__ mu,
             float* __restrict__ rstd) {
  const int row = blockIdx.x;
  const int tid = threadIdx.x;
  const s16x4 v = ((const s16x4*)(oat + (size_t)row * 1024))[tid];
  const float f0 = bf2f(v[0]), f1 = bf2f(v[1]), f2 = bf2f(v[2]), f3 = bf2f(v[3]);
  float s = f0 + f1 + f2 + f3;
  float s2 = f0 * f0 + f1 * f1 + f2 * f2 + f3 * f3;
#pragma unroll
  for (int o = 32; o > 0; o >>= 1) {
    s += __shfl_down(s, o);
    s2 += __shfl_down(s2, o);
  }
  __shared__ float red[8];
  const int wid = tid >> 6, lane = tid & 63;
  if (lane == 0) { red[wid] = s; red[wid + 4] = s2; }
  __syncthreads();
  if (tid == 0) {
    const float ts = red[0] + red[1] + red[2] + red[3];
    const float ts2 = red[4] + red[5] + red[6] + red[7];
    const float m = ts * (1.0f / 1024.0f);
    const float var = ts2 * (1.0f / 1024.0f) - m * m;
    mu[row] = m;
    rstd[row] = rsqrtf(var + 1e-5f);
  }
}

extern "C" void kernel_launch(void* const* d_in, const int* in_sizes, int n_in,
                              void* d_out, int out_size, void* d_ws, size_t ws_size,
                              hipStream_t stream) {
  const float* x = (const float*)d_in[0];
  const float* Wq = (const float*)d_in[1];
  const float* bq = (const float*)d_in[2];
  const float* Wk = (const float*)d_in[3];
  const float* bk = (const float*)d_in[4];
  const float* Wv = (const float*)d_in[5];
  const float* bv = (const float*)d_in[6];
  const float* Wo = (const float*)d_in[7];
  const float* bo = (const float*)d_in[8];
  const float* lng = (const float*)d_in[9];
  const float* lnb = (const float*)d_in[10];

  char* ws = (char*)d_ws;
  short* xb = (short*)(ws + 0);              // 33.5MB x bf16; reused as oat bf16 after gemm5
  short* wt = (short*)(ws + 33554432);       // 12.6MB 6x weights bf16
  short* q = (short*)(ws + 46137344);        // 33.5MB q bf16
  short* kst = (short*)(ws + 79691776);      // 67MB ks_t bf16 [k,b,h,d,n]
  short* vst = (short*)(ws + 146800640);     // 67MB vs_t bf16
  float* P = (float*)(ws + 213909504);       // 8.4MB state partials fp32
  short* stt = (short*)(ws + 222298112);     // 512KB state^T bf16
  // dead-after-states_k vst region reuse (ut_k/stats_k run after states_k):
  float* uu = (float*)(ws + 146800640);      // 4KB
  float* tt = (float*)(ws + 146804736);      // 4KB
  float* mu = (float*)(ws + 146808832);      // 64KB
  float* rstd = (float*)(ws + 146874368);    // 64KB
  short* oat = xb;                            // out_att bf16 (xb dead after gemm5)

  convx_k<<<4096, 256, 0, stream>>>(x, xb, 16777216 / 4);
  twc_k<<<dim3(32, 32, 6), dim3(32, 8), 0, stream>>>(Wq, Wk, Wv, Wo, lng, wt);

  gemm256p_k<0><<<1280, 512, 131072, stream>>>(xb, wt, bq, bk, bv, q, kst,
                                               nullptr, nullptr, nullptr, nullptr, nullptr);

  states_k<<<dim3(64, 4, 2), 256, 0, stream>>>(kst, vst, P);
  state_mul_k<<<64, 256, 0, stream>>>(P, stt);
  ut_k<<<16, 256, 0, stream>>>(Wo, lng, lnb, bo, uu, tt);
  attn_k<<<dim3(32, 64), 256, 0, stream>>>(q, stt, oat);
  stats_k<<<16384, 256, 0, stream>>>(oat, mu, rstd);

  gemm256p_k<1><<<256, 512, 131072, stream>>>(oat, wt + 5242880, nullptr, nullptr, nullptr,
                                              nullptr, nullptr, mu, rstd, uu, tt,
                                              (float*)d_out);
}